// Round 3
// baseline (341.048 us; speedup 1.0000x reference)
//
#include <hip/hip_runtime.h>
#include <hip/hip_bf16.h>

typedef _Float16 h8 __attribute__((ext_vector_type(8)));
typedef _Float16 h4v __attribute__((ext_vector_type(4)));
typedef float f4 __attribute__((ext_vector_type(4)));

#define T_ 4
#define B_ 8
#define N_ 512
#define C_ 512
#define H_ 8
#define D_ 64
#define BNR 4096
#define EPSf 1e-5f
#define F16_MIN_NORM 6.1035156e-05f
#define INV4096 0.000244140625f

// ---- fp32 -> (h1 + 2^-12 * h2) f16 split, 4 elements/thread ----
__global__ __launch_bounds__(256)
void split_f16(const float* __restrict__ in, _Float16* __restrict__ h1,
               _Float16* __restrict__ h2, int n4)
{
    int i = blockIdx.x * 256 + threadIdx.x;
    if (i >= n4) return;
    float4 x = reinterpret_cast<const float4*>(in)[i];
    h4v a, b;
    #pragma unroll
    for (int j = 0; j < 4; ++j) {
        float xv = (&x.x)[j];
        float hi = (fabsf(xv) >= F16_MIN_NORM) ? xv : 0.0f;   // avoid f16 subnormal x1
        _Float16 h = (_Float16)hi;
        float r = (xv - (float)h) * 4096.0f;                  // normal-range residual
        a[j] = h; b[j] = (_Float16)r;
    }
    reinterpret_cast<h4v*>(h1)[i] = a;
    reinterpret_cast<h4v*>(h2)[i] = b;
}

// ---- MFMA GEMM (f16 split) + BN(eval) + LIF over T, epilogue-free ----
// Block: 64 bn-rows x 64 cols x 4t. Wave w owns rows [16w,16w+16) for ALL 4 t
// (B-frags shared across t; LIF fully in registers -> no epilogue LDS).
// A staged via global_load_lds (16B) into [spl][t][kq][m][16B] (linear in lane
// order: slot = q*1024 + lane*16), double-buffered. W read direct from global
// (L2-resident, L1-dedup across the 4 waves).
// MODE 0: A=(A1,A2) split, 3 mfma/frag, out bf16 head-split (T,B,H,N,D).
// MODE 1: A=A1 exact f16 spikes, 2 mfma/frag, out fp32 (T,B,N,C).
template<int MODE>
__global__ __launch_bounds__(256, 2)
void mfma_gemm_bn_lif(const _Float16* __restrict__ A1, const _Float16* __restrict__ A2,
                      const _Float16* __restrict__ W1, const _Float16* __restrict__ W2,
                      const float* __restrict__ bias, const float* __restrict__ gam,
                      const float* __restrict__ bet, const float* __restrict__ mea,
                      const float* __restrict__ rva,
                      __hip_bfloat16* __restrict__ out_hs, float* __restrict__ out_plain)
{
    constexpr int ABUF = (MODE == 0) ? 32768 : 16384;   // bytes per k-step A buffer
    constexpr int NP = ABUF / 4096;                     // gll iterations (8 / 4)
    __shared__ __align__(16) char smem[2 * ABUF];

    const int tid = threadIdx.x;
    const int id = blockIdx.x;
    const int bt = (id & 7) * 8 + ((id >> 3) & 7);      // XCD-aware swizzle
    const int ct = id >> 6;
    const int row0 = bt * 64, col0 = ct * 64;
    const int wv = tid >> 6, lane = tid & 63;
    const int lr = lane & 15, lk = lane >> 4;

    f4 accA[4][4], accB[4][4];
    #pragma unroll
    for (int t = 0; t < 4; ++t)
        #pragma unroll
        for (int ni = 0; ni < 4; ++ni) { accA[t][ni] = (f4)0.0f; accB[t][ni] = (f4)0.0f; }

    // stage k-slice [k0,k0+32) of A into buffer b
    auto stage = [&](int k0, int b) {
        #pragma unroll
        for (int p = 0; p < NP; ++p) {
            const int q = p * 4 + wv;                   // slot = q*1024 + lane*16
            const int kq = q & 3, t = (q >> 2) & 3, spl = q >> 4;
            const _Float16* src = (MODE == 0 && spl) ? A2 : A1;
            const _Float16* g = src + (size_t)(t * BNR + row0 + lane) * C_ + k0 + kq * 8;
            char* dst = smem + b * ABUF + p * 4096 + wv * 1024;   // wave-uniform base
            __builtin_amdgcn_global_load_lds(
                (const __attribute__((address_space(1))) unsigned int*)g,
                (__attribute__((address_space(3))) unsigned int*)dst, 16, 0, 0);
        }
    };

    stage(0, 0);
    int buf = 0;
    for (int k0 = 0; k0 < C_; k0 += 32) {
        __syncthreads();                                // drains prev stage (vmcnt 0)
        // W frags first: waiting on them then costs vmcnt(8), keeping prefetch in flight
        h8 w1f[4], w2f[4];
        #pragma unroll
        for (int ni = 0; ni < 4; ++ni) {
            const size_t wo = (size_t)(col0 + ni * 16 + lr) * C_ + k0 + lk * 8;
            w1f[ni] = *reinterpret_cast<const h8*>(W1 + wo);
            w2f[ni] = *reinterpret_cast<const h8*>(W2 + wo);
        }
        if (k0 + 32 < C_) stage(k0 + 32, buf ^ 1);      // prefetch next k-slice
        const char* ab = smem + buf * ABUF;
        h8 a1[4], a2[4];
        #pragma unroll
        for (int t = 0; t < 4; ++t) {
            const int ao = t * 4096 + lk * 1024 + (wv * 16 + lr) * 16;
            a1[t] = *reinterpret_cast<const h8*>(ab + ao);
            if (MODE == 0) a2[t] = *reinterpret_cast<const h8*>(ab + 16384 + ao);
        }
        #pragma unroll
        for (int ni = 0; ni < 4; ++ni)
            #pragma unroll
            for (int t = 0; t < 4; ++t) {
                accA[t][ni] = __builtin_amdgcn_mfma_f32_16x16x32_f16(a1[t], w1f[ni], accA[t][ni], 0, 0, 0);
                accB[t][ni] = __builtin_amdgcn_mfma_f32_16x16x32_f16(a1[t], w2f[ni], accB[t][ni], 0, 0, 0);
                if (MODE == 0)
                    accB[t][ni] = __builtin_amdgcn_mfma_f32_16x16x32_f16(a2[t], w1f[ni], accB[t][ni], 0, 0, 0);
            }
        buf ^= 1;
    }

    // ---- in-register BN + LIF epilogue (wave owns all 4 t of its rows) ----
    #pragma unroll
    for (int ni = 0; ni < 4; ++ni) {
        const int c = col0 + ni * 16 + lr;
        const float sc = gam[c] * (1.0f / sqrtf(rva[c] + EPSf));
        const float bi = bias[c], mn = mea[c], be = bet[c];
        #pragma unroll
        for (int r = 0; r < 4; ++r) {
            const int bn = row0 + wv * 16 + lk * 4 + r;  // C/D: row=(l>>4)*4+reg, col=l&15
            float vm = 0.0f;
            #pragma unroll
            for (int t = 0; t < 4; ++t) {
                const float res = accA[t][ni][r] + INV4096 * accB[t][ni][r];
                const float y = ((res + bi) - mn) * sc + be;
                vm = vm + (y - vm) * 0.5f;
                const float s = (vm >= 1.0f) ? 1.0f : 0.0f;
                vm = (s != 0.0f) ? 0.0f : vm;
                if (MODE == 0) {
                    const int b = bn >> 9, n = bn & 511;
                    out_hs[((((size_t)t * B_ + b) * H_ + ct) * N_ + n) * D_ + ni * 16 + lr] =
                        __float2bfloat16(s);
                } else {
                    out_plain[((size_t)t * BNR + bn) * C_ + c] = s;
                }
            }
        }
    }
}

// ---- kv[d1][d2] = sum_n k[n,d1]*v[n,d2] per (t,b,h) ----
__global__ __launch_bounds__(256)
void ktv_kernel(const __hip_bfloat16* __restrict__ sk, const __hip_bfloat16* __restrict__ sv,
                float* __restrict__ kv)
{
    __shared__ __hip_bfloat16 kl[64][64];
    __shared__ __hip_bfloat16 vl[64][64];
    const int tbh = blockIdx.x;
    const int tid = threadIdx.x;
    const int tx = tid & 15, ty = tid >> 4;
    const size_t base = (size_t)tbh * N_ * D_;
    float acc[4][4] = {};
    for (int n0 = 0; n0 < N_; n0 += 64) {
        __syncthreads();
        #pragma unroll
        for (int p = 0; p < 2; ++p) {
            const int idx = tid + p * 256;
            const int r = idx >> 3, c8 = (idx & 7) * 8;
            *reinterpret_cast<float4*>(&kl[r][c8]) =
                *reinterpret_cast<const float4*>(&sk[base + (size_t)(n0 + r) * D_ + c8]);
            *reinterpret_cast<float4*>(&vl[r][c8]) =
                *reinterpret_cast<const float4*>(&sv[base + (size_t)(n0 + r) * D_ + c8]);
        }
        __syncthreads();
        for (int nn = 0; nn < 64; ++nn) {
            float a[4], b[4];
            #pragma unroll
            for (int i = 0; i < 4; ++i) a[i] = __bfloat162float(kl[nn][ty * 4 + i]);
            #pragma unroll
            for (int j = 0; j < 4; ++j) b[j] = __bfloat162float(vl[nn][tx * 4 + j]);
            #pragma unroll
            for (int i = 0; i < 4; ++i)
                #pragma unroll
                for (int j = 0; j < 4; ++j)
                    acc[i][j] = fmaf(a[i], b[j], acc[i][j]);
        }
    }
    float* out = kv + (size_t)tbh * 4096;
    #pragma unroll
    for (int i = 0; i < 4; ++i)
        #pragma unroll
        for (int j = 0; j < 4; ++j)
            out[(ty * 4 + i) * 64 + tx * 4 + j] = acc[i][j];
}

// ---- o = 0.125 * q @ kv, fused attn-LIF (vth=0.5); writes f16 spikes (T,B,N,C) ----
__global__ __launch_bounds__(256)
void qkv_lif_kernel(const __hip_bfloat16* __restrict__ sq, const float* __restrict__ kv,
                    _Float16* __restrict__ osp)
{
    __shared__ float kvl[64][64];
    __shared__ __hip_bfloat16 ql[64][64];
    const int nt = blockIdx.x, b = blockIdx.y, h = blockIdx.z;
    const int tid = threadIdx.x;
    const int tx = tid & 15, ty = tid >> 4;
    const int n0 = nt * 64;
    float v[4][4] = {};
    for (int t = 0; t < T_; ++t) {
        const int tbh = (t * B_ + b) * H_ + h;
        __syncthreads();
        #pragma unroll
        for (int p = 0; p < 16; ++p) {
            const int idx = p * 256 + tid;
            kvl[idx >> 6][idx & 63] = kv[(size_t)tbh * 4096 + idx];
        }
        #pragma unroll
        for (int p = 0; p < 2; ++p) {
            const int idx = tid + p * 256;
            const int r = idx >> 3, c8 = (idx & 7) * 8;
            *reinterpret_cast<float4*>(&ql[r][c8]) =
                *reinterpret_cast<const float4*>(&sq[((size_t)tbh * N_ + n0 + r) * D_ + c8]);
        }
        __syncthreads();
        float acc[4][4] = {};
        for (int dd = 0; dd < 64; ++dd) {
            float a[4], bb[4];
            #pragma unroll
            for (int i = 0; i < 4; ++i) a[i] = __bfloat162float(ql[ty * 4 + i][dd]);
            #pragma unroll
            for (int j = 0; j < 4; ++j) bb[j] = kvl[dd][tx * 4 + j];
            #pragma unroll
            for (int i = 0; i < 4; ++i)
                #pragma unroll
                for (int j = 0; j < 4; ++j)
                    acc[i][j] = fmaf(a[i], bb[j], acc[i][j]);
        }
        #pragma unroll
        for (int i = 0; i < 4; ++i)
            #pragma unroll
            for (int j = 0; j < 4; ++j) {
                const float y = 0.125f * acc[i][j];     // exact (integer counts)
                float vv = v[i][j];
                vv = vv + (y - vv) * 0.5f;
                const float s = (vv >= 0.5f) ? 1.0f : 0.0f;
                osp[((size_t)(t * B_ + b) * N_ + n0 + ty * 4 + i) * C_ + h * 64 + tx * 4 + j] = (_Float16)s;
                v[i][j] = (s != 0.0f) ? 0.0f : vv;
            }
    }
}

extern "C" void kernel_launch(void* const* d_in, const int* in_sizes, int n_in,
                              void* d_out, int out_size, void* d_ws, size_t ws_size,
                              hipStream_t stream)
{
    const float* x = (const float*)d_in[0];
    const float *W[4], *bia[4], *gam[4], *bet[4], *mea[4], *rva[4];
    for (int br = 0; br < 4; ++br) {
        W[br]   = (const float*)d_in[1 + 6 * br + 0];
        bia[br] = (const float*)d_in[1 + 6 * br + 1];
        gam[br] = (const float*)d_in[1 + 6 * br + 2];
        bet[br] = (const float*)d_in[1 + 6 * br + 3];
        mea[br] = (const float*)d_in[1 + 6 * br + 4];
        rva[br] = (const float*)d_in[1 + 6 * br + 5];
    }
    char* ws = (char*)d_ws;
    _Float16* x1 = (_Float16*)(ws + 0);
    _Float16* x2 = (_Float16*)(ws + 16777216);
    __hip_bfloat16* sq = (__hip_bfloat16*)(ws + 33554432);
    __hip_bfloat16* sk = (__hip_bfloat16*)(ws + 50331648);
    __hip_bfloat16* sv = (__hip_bfloat16*)(ws + 67108864);
    _Float16* w1[4], *w2[4];
    for (int br = 0; br < 4; ++br) {
        w1[br] = (_Float16*)(ws + 83886080 + (size_t)br * 1048576);
        w2[br] = (_Float16*)(ws + 83886080 + (size_t)br * 1048576 + 524288);
    }
    float*    kv  = (float*)(ws + 16777216);     // aliases x2 (dead after 3rd GEMM)
    _Float16* osp = (_Float16*)(ws + 0);         // aliases x1 (dead after 3rd GEMM)

    dim3 blk(256);
    split_f16<<<dim3(8192), blk, 0, stream>>>(x, x1, x2, 2097152);
    for (int br = 0; br < 4; ++br)
        split_f16<<<dim3(256), blk, 0, stream>>>(W[br], w1[br], w2[br], 65536);

    mfma_gemm_bn_lif<0><<<dim3(512), blk, 0, stream>>>(x1, x2, w1[0], w2[0],
        bia[0], gam[0], bet[0], mea[0], rva[0], sq, nullptr);
    mfma_gemm_bn_lif<0><<<dim3(512), blk, 0, stream>>>(x1, x2, w1[1], w2[1],
        bia[1], gam[1], bet[1], mea[1], rva[1], sk, nullptr);
    mfma_gemm_bn_lif<0><<<dim3(512), blk, 0, stream>>>(x1, x2, w1[2], w2[2],
        bia[2], gam[2], bet[2], mea[2], rva[2], sv, nullptr);

    ktv_kernel<<<dim3(T_ * B_ * H_), blk, 0, stream>>>(sk, sv, kv);
    qkv_lif_kernel<<<dim3(N_ / 64, B_, H_), blk, 0, stream>>>(sq, kv, osp);

    mfma_gemm_bn_lif<1><<<dim3(512), blk, 0, stream>>>(osp, nullptr, w1[3], w2[3],
        bia[3], gam[3], bet[3], mea[3], rva[3], nullptr, (float*)d_out);
}